// Round 15
// baseline (33.446 us; speedup 1.0000x reference)
//
#include <hip/hip_runtime.h>

// Chamfer min-matching loss, B=8, P=4096, D=2, fp32 — exact NN, fully fused:
// each block self-sorts its target side in LDS (counting sort by x-bin),
// rank-sorts its 256-query slice for lane adjacency, then does the fixed
// 256-candidate window scan + certificate + wave-cooperative rescue (R14).
// Dispatch 1 is a nanokernel zeroing out (atomicAdd target).
// R14 accounting: 16-block xSort + global round-trip was ~half the work;
// self-sort spreads it over 256 otherwise-idle CUs and stays in LDS.

#define NB    8
#define NP    4096
#define XBINS 2048
#define W     0.0048828125f      // 10 / 2048
#define XMIN  -5.0f
#define INVW  204.8f
#define WH    128                // half-window (256 candidates)

__device__ __forceinline__ int xbin(float x) {
    int i = (int)((x - XMIN) * INVW);
    return i < 0 ? 0 : (i > XBINS - 1 ? XBINS - 1 : i);
}

__global__ void zeroOut(float* __restrict__ out) {
    if (threadIdx.x == 0) *out = 0.0f;
}

#define FOREACH8(M) M(0) M(1) M(2) M(3) M(4) M(5) M(6) M(7)

__global__ __launch_bounds__(256) void sortSearch(const float* __restrict__ pred,
                                                  const float* __restrict__ gt,
                                                  float* __restrict__ out) {
    __shared__ __align__(16) float2 sp[NP];            // 32 KB sorted target
    __shared__ __align__(16) unsigned cnt[XBINS];      // 8 KB hist/cursors/ends
    __shared__ __align__(16) float2 qs2[256];          // 2 KB sorted queries
    __shared__ __align__(8)  unsigned short jb[256];   // 0.5 KB query bins
    __shared__ float wsum[4];
    __shared__ unsigned waveTot[4];

    int t     = threadIdx.x;
    int bid   = blockIdx.x;        // 0..255
    int qs    = bid & 15;          // dir*8 + b
    int slice = bid >> 4;          // 0..15
    int b = qs & 7, dir = qs >> 3; // dir0: query=pred, target=gt

    const float2* tp = (const float2*)(dir ? pred : gt) + (size_t)b * NP;
    const float2* qp = (const float2*)(dir ? gt : pred) + (size_t)b * NP;

    // zero histogram; load my query early (independent)
#pragma unroll
    for (int i = 0; i < XBINS / 256; ++i) cnt[t + i * 256] = 0;
    float2 myq = qp[slice * 256 + t];
    __syncthreads();

    // ---- pass 1: stage 16 target pts in NAMED registers + LDS histogram ----
    const float4* tp4 = (const float4*)tp;
#define DECLV(i) float4 v##i = tp4[t + (i) * 256]; \
    atomicAdd(&cnt[xbin(v##i.x)], 1u); atomicAdd(&cnt[xbin(v##i.z)], 1u);
    FOREACH8(DECLV)
#undef DECLV
    __syncthreads();

    // ---- exclusive scan over 2048 bins (8 per thread + shfl wave scan) ----
    unsigned local = 0;
#pragma unroll
    for (int i = 0; i < 8; ++i) local += cnt[t * 8 + i];
    unsigned inc = local;
#pragma unroll
    for (int o = 1; o < 64; o <<= 1) {
        unsigned n = __shfl_up(inc, o, 64);
        if ((t & 63) >= o) inc += n;
    }
    if ((t & 63) == 63) waveTot[t >> 6] = inc;
    __syncthreads();
    unsigned wbase = 0;
#pragma unroll
    for (int w = 0; w < 4; ++w) if (w < (t >> 6)) wbase += waveTot[w];
    unsigned run = wbase + inc - local;
#pragma unroll
    for (int i = 0; i < 8; ++i) {
        unsigned c = cnt[t * 8 + i];
        cnt[t * 8 + i] = run;        // bin starts (become cursors)
        run += c;
    }
    __syncthreads();

    // ---- scatter from registers into sorted LDS array ----
#define SCAT(i) { \
    unsigned p0 = atomicAdd(&cnt[xbin(v##i.x)], 1u); \
    sp[p0] = (float2){v##i.x, v##i.y}; \
    unsigned p1 = atomicAdd(&cnt[xbin(v##i.z)], 1u); \
    sp[p1] = (float2){v##i.z, v##i.w}; }
    FOREACH8(SCAT)
#undef SCAT
    // after scatter: cnt[j] = end[j] = start[j+1]

    // ---- query rank-sort (lane adjacency for the window scan) ----
    int j = xbin(myq.x);
    jb[t] = (unsigned short)j;
    __syncthreads();
    int rank = 0;
    const uint2* jbp = (const uint2*)jb;
#pragma unroll 8
    for (int kk = 0; kk < 64; ++kk) {
        uint2 w2 = jbp[kk];          // broadcast read, 4 bins
        int k0 = kk * 4;
        int j0 = w2.x & 0xffff, j1 = w2.x >> 16;
        int j2 = w2.y & 0xffff, j3 = w2.y >> 16;
        rank += (j0 < j) || (j0 == j && k0 < t);
        rank += (j1 < j) || (j1 == j && k0 + 1 < t);
        rank += (j2 < j) || (j2 == j && k0 + 2 < t);
        rank += (j3 < j) || (j3 == j && k0 + 3 < t);
    }
    qs2[rank] = myq;
    __syncthreads();
    myq = qs2[t];
    float qx = myq.x, qy = myq.y;

    // ---- rank lookup + fixed 256-candidate window scan ----
    int jq = xbin(qx);
    int r0 = (jq == 0) ? 0 : (int)cnt[jq - 1];   // cnt holds ends => start[jq]

    int w0 = r0 - WH;
    if (w0 < 0) w0 = 0;
    if (w0 > NP - 2 * WH) w0 = NP - 2 * WH;
    w0 &= ~1;

    float best = 3.402823466e+38f;
    const float4* spc = (const float4*)sp;
    int base = w0 >> 1;
#pragma unroll 8
    for (int k = 0; k < WH; ++k) {
        float4 v = spc[base + k];
        float dx0 = qx - v.x, dy0 = qy - v.y;
        float dx1 = qx - v.z, dy1 = qy - v.w;
        float d0 = fmaf(dx0, dx0, dy0 * dy0);
        float d1 = fmaf(dx1, dx1, dy1 * dy1);
        best = fminf(fminf(best, d0), d1);       // v_min3_f32
    }

    // ---- certificate (bin-sorted: earlier bins have x <= sp[w0].x + W) ----
    float lbL = (w0 > 0)           ? fmaxf(qx - sp[w0].x - W, 0.0f)               : 3.0e38f;
    float lbR = (w0 + 2 * WH < NP) ? fmaxf(sp[w0 + 2 * WH - 1].x - W - qx, 0.0f)  : 3.0e38f;
    bool uncert = (lbL * lbL < best) || (lbR * lbR < best);

    // ---- wave-cooperative rescue (exact full scan per uncertified lane) ----
    unsigned long long mask = __ballot(uncert);
    int lane = t & 63;
    while (mask) {
        int l = __ffsll((long long)mask) - 1;
        mask &= mask - 1;
        float qlx = __shfl(qx, l, 64);
        float qly = __shfl(qy, l, 64);
        float rb = 3.402823466e+38f;
#pragma unroll 4
        for (int i = 0; i < 32; ++i) {
            float4 v = spc[lane + i * 64];
            float dx0 = qlx - v.x, dy0 = qly - v.y;
            float dx1 = qlx - v.z, dy1 = qly - v.w;
            rb = fminf(rb, fmaf(dx0, dx0, dy0 * dy0));
            rb = fminf(rb, fmaf(dx1, dx1, dy1 * dy1));
        }
#pragma unroll
        for (int o = 32; o > 0; o >>= 1) rb = fminf(rb, __shfl_xor(rb, o, 64));
        if (lane == l) best = rb;
    }

    // ---- reduce + accumulate ----
    float v = sqrtf(fmaxf(best, 1e-12f));
#pragma unroll
    for (int o = 32; o > 0; o >>= 1) v += __shfl_down(v, o, 64);
    if ((t & 63) == 0) wsum[t >> 6] = v;
    __syncthreads();
    if (t == 0)
        atomicAdd(out, ((wsum[0] + wsum[1]) + (wsum[2] + wsum[3])) *
                           (0.5f / (float)(NB * NP)));
}

extern "C" void kernel_launch(void* const* d_in, const int* in_sizes, int n_in,
                              void* d_out, int out_size, void* d_ws, size_t ws_size,
                              hipStream_t stream) {
    const float* pred = (const float*)d_in[0];
    const float* gt   = (const float*)d_in[1];
    float*       out  = (float*)d_out;

    (void)in_sizes; (void)n_in; (void)out_size; (void)d_ws; (void)ws_size;

    zeroOut<<<1, 64, 0, stream>>>(out);
    sortSearch<<<256, 256, 0, stream>>>(pred, gt, out);
}

// Round 16
// 22.643 us; speedup vs baseline: 1.4771x; 1.4771x over previous
//
#include <hip/hip_runtime.h>

// Chamfer min-matching loss, B=8, P=4096, D=2, fp32 — exact NN via x-sorted
// rank-window scan + wave-cooperative rescue (R14 winSearch verbatim).
// xSort v2: one coalesced read into NAMED registers, LDS histogram + shfl
// scan, scatter into LDS (cheap random ds_write), then COALESCED float4
// write-out of the sorted array. R14's xSort did 2 global reads + 4096
// random 8B global stores on 16 CUs — the suspected ~10 us.

#define NB    8
#define NP    4096
#define XBINS 2048
#define W     0.0048828125f      // 10 / 2048
#define XMIN  -5.0f
#define INVW  204.8f
#define BSSTR (XBINS + 4)        // u32 stride, 16B-aligned
#define WH    128                // half-window (256 candidates)

__device__ __forceinline__ int xbin(float x) {
    int i = (int)((x - XMIN) * INVW);
    return i < 0 ? 0 : (i > XBINS - 1 ? XBINS - 1 : i);
}

#define FOREACH8(M) M(0) M(1) M(2) M(3) M(4) M(5) M(6) M(7)

// ---- Kernel 1: counting sort by x-bin, one block per (batch, side) ----
__global__ __launch_bounds__(256) void xSort(const float* __restrict__ pred,
                                             const float* __restrict__ gt,
                                             float2* __restrict__ P,      // [16][NP]
                                             unsigned* __restrict__ BS,   // [16][BSSTR]
                                             float* __restrict__ out) {
    __shared__ __align__(16) float2 sp[NP];     // 32 KB sorted staging
    __shared__ unsigned cnt[XBINS];             // 8 KB hist -> starts -> cursors
    __shared__ unsigned waveTot[4];

    int t = threadIdx.x;
    int s = blockIdx.x;                 // 0..15
    int b = s >> 1, side = s & 1;

    if (s == 0 && t == 0) *out = 0.0f;  // stream order: before winSearch atomics

    const float2* src = (const float2*)(side ? gt : pred) + (size_t)b * NP;
    float2*   dst = P  + (size_t)s * NP;
    unsigned* bs  = BS + (size_t)s * BSSTR;

#pragma unroll
    for (int i = 0; i < XBINS / 256; ++i) cnt[t + i * 256] = 0;
    __syncthreads();

    // one coalesced read into named registers + histogram
    const float4* src4 = (const float4*)src;
#define DECLV(i) float4 v##i = src4[t + (i) * 256]; \
    atomicAdd(&cnt[xbin(v##i.x)], 1u); atomicAdd(&cnt[xbin(v##i.z)], 1u);
    FOREACH8(DECLV)
#undef DECLV
    __syncthreads();

    // exclusive scan over 2048 bins (8 bins/thread + shfl wave scan)
    unsigned local = 0;
#pragma unroll
    for (int i = 0; i < 8; ++i) local += cnt[t * 8 + i];
    unsigned inc = local;
#pragma unroll
    for (int o = 1; o < 64; o <<= 1) {
        unsigned n = __shfl_up(inc, o, 64);
        if ((t & 63) >= o) inc += n;
    }
    if ((t & 63) == 63) waveTot[t >> 6] = inc;
    __syncthreads();
    unsigned wbase = 0;
#pragma unroll
    for (int w = 0; w < 4; ++w) if (w < (t >> 6)) wbase += waveTot[w];
    unsigned run = wbase + inc - local;
#pragma unroll
    for (int i = 0; i < 8; ++i) {
        unsigned c = cnt[t * 8 + i];
        cnt[t * 8 + i] = run;           // bin starts
        run += c;
    }
    __syncthreads();

    // publish starts (coalesced) BEFORE cursors mutate
    for (int i = t; i < XBINS; i += 256) bs[i] = cnt[i];
    __syncthreads();

    // scatter from registers into LDS sorted array (cheap random ds_write)
#define SCAT(i) { \
    unsigned p0 = atomicAdd(&cnt[xbin(v##i.x)], 1u); \
    sp[p0] = (float2){v##i.x, v##i.y}; \
    unsigned p1 = atomicAdd(&cnt[xbin(v##i.z)], 1u); \
    sp[p1] = (float2){v##i.z, v##i.w}; }
    FOREACH8(SCAT)
#undef SCAT
    __syncthreads();

    // coalesced write-out of the sorted array
    const float4* sp4 = (const float4*)sp;
    float4*       dst4 = (float4*)dst;
#pragma unroll
    for (int i = 0; i < 8; ++i) dst4[t + i * 256] = sp4[t + i * 256];
}

// ---- Kernel 2: fixed-window scan + wave-cooperative rescue (R14 verbatim) ----
__global__ __launch_bounds__(256) void winSearch(const float2* __restrict__ P,
                                                 const unsigned* __restrict__ BS,
                                                 float* __restrict__ out) {
    __shared__ __align__(16) float2 sp[NP];             // 32 KB sorted target
    __shared__ __align__(16) unsigned short sbs[XBINS]; // 4 KB bin starts

    int t     = threadIdx.x;
    int bid   = blockIdx.x;        // 0..255
    int qs    = bid & 15;          // dir*8 + b
    int slice = bid >> 4;          // 0..15
    int b = qs & 7, dir = qs >> 3;

    int tgt = b * 2 + (1 - dir);   // sorted target side
    const float2*   tp = P  + (size_t)tgt * NP;
    const unsigned* bs = BS + (size_t)tgt * BSSTR;

    // stage sorted points (32 KB) + bin starts packed to u16 (4 KB)
    const float4* tp4 = (const float4*)tp;
    float4*       sp4w = (float4*)sp;
#pragma unroll
    for (int i = 0; i < 8; ++i) sp4w[t + i * 256] = tp4[t + i * 256];
    const uint4* bs4  = (const uint4*)bs;
    uint2*       sbs2 = (uint2*)sbs;
#pragma unroll
    for (int i = 0; i < 2; ++i) {
        uint4 v = bs4[t + i * 256];
        sbs2[t + i * 256] = make_uint2(v.x | (v.y << 16), v.z | (v.w << 16));
    }

    // query from the SORTED query-side array (coalesced; order-invariant mean)
    const float2* qarr = P + (size_t)(b * 2 + dir) * NP;
    float2 q = qarr[slice * 256 + t];
    __syncthreads();

    float qx = q.x, qy = q.y;
    int r0 = (int)sbs[xbin(qx)];

    int w0 = r0 - WH;
    if (w0 < 0) w0 = 0;
    if (w0 > NP - 2 * WH) w0 = NP - 2 * WH;
    w0 &= ~1;                       // 16B-align the b128 stream

    float best = 3.402823466e+38f;
    const float4* spc = (const float4*)sp;
    int base = w0 >> 1;
#pragma unroll 8
    for (int k = 0; k < WH; ++k) {  // 128 x b128 = 256 candidates, fixed trip
        float4 v = spc[base + k];
        float dx0 = qx - v.x, dy0 = qy - v.y;
        float dx1 = qx - v.z, dy1 = qy - v.w;
        float d0 = fmaf(dx0, dx0, dy0 * dy0);
        float d1 = fmaf(dx1, dx1, dy1 * dy1);
        best = fminf(fminf(best, d0), d1);   // v_min3_f32
    }

    // certificate (bin-sorted: k<w0 => p.x <= sp[w0].x + W, mirrored)
    float lbL = (w0 > 0)           ? fmaxf(qx - sp[w0].x - W, 0.0f)              : 3.0e38f;
    float lbR = (w0 + 2 * WH < NP) ? fmaxf(sp[w0 + 2 * WH - 1].x - W - qx, 0.0f) : 3.0e38f;
    bool uncert = (lbL * lbL < best) || (lbR * lbR < best);

    // wave-cooperative rescue: full exact scan per uncertified lane
    unsigned long long mask = __ballot(uncert);
    int lane = t & 63;
    while (mask) {
        int l = __ffsll((long long)mask) - 1;
        mask &= mask - 1;
        float qlx = __shfl(qx, l, 64);
        float qly = __shfl(qy, l, 64);
        float rb = 3.402823466e+38f;
#pragma unroll 4
        for (int i = 0; i < 32; ++i) {      // 64 lanes x 32 x 2 pts = all 4096
            float4 v = spc[lane + i * 64];
            float dx0 = qlx - v.x, dy0 = qly - v.y;
            float dx1 = qlx - v.z, dy1 = qly - v.w;
            rb = fminf(rb, fmaf(dx0, dx0, dy0 * dy0));
            rb = fminf(rb, fmaf(dx1, dx1, dy1 * dy1));
        }
#pragma unroll
        for (int o = 32; o > 0; o >>= 1) rb = fminf(rb, __shfl_xor(rb, o, 64));
        if (lane == l) best = rb;           // exact full-scan result
    }

    float v = sqrtf(fmaxf(best, 1e-12f));

#pragma unroll
    for (int o = 32; o > 0; o >>= 1) v += __shfl_down(v, o, 64);

    __shared__ float wsum[4];
    if ((t & 63) == 0) wsum[t >> 6] = v;
    __syncthreads();
    if (t == 0)
        atomicAdd(out, ((wsum[0] + wsum[1]) + (wsum[2] + wsum[3])) *
                           (0.5f / (float)(NB * NP)));
}

extern "C" void kernel_launch(void* const* d_in, const int* in_sizes, int n_in,
                              void* d_out, int out_size, void* d_ws, size_t ws_size,
                              hipStream_t stream) {
    const float* pred = (const float*)d_in[0];
    const float* gt   = (const float*)d_in[1];
    float*       out  = (float*)d_out;

    float2*   P  = (float2*)d_ws;                       // 16 * 4096 * 8 B = 512 KB
    unsigned* BS = (unsigned*)(P + (size_t)16 * NP);    // 16 * 2052 * 4 B

    (void)in_sizes; (void)n_in; (void)out_size; (void)ws_size;

    xSort<<<16, 256, 0, stream>>>(pred, gt, P, BS, out);
    winSearch<<<256, 256, 0, stream>>>(P, BS, out);
}